// Round 1
// baseline (350.641 us; speedup 1.0000x reference)
//
#include <hip/hip_runtime.h>
#include <math.h>

#define BB 8
#define CC 1024
#define HH 56
#define WW 56
#define NB 256
#define NCLS 30
#define BC (BB * CC)            // 8192
#define PLANE (HH * WW)         // 3136
#define HISTN (HH * WW * NB)    // 802816 u32 entries
#define SLICES 4

// ---------------------------------------------------------------------------
// Kernel 1: per-(h,w)-cell histograms. One block owns one h row for one
// bc-slice; LDS hist [56][256] (57 KB), random-bin LDS atomics are ~free,
// then one global atomicAdd flush per nonzero entry (3.2M total at SLICES=4).
// ---------------------------------------------------------------------------
__global__ __launch_bounds__(512) void hist_kernel(const float* __restrict__ x,
                                                   unsigned* __restrict__ hist) {
    __shared__ unsigned lh[WW * NB];
    const int h = blockIdx.x % HH;
    const int slice = blockIdx.x / HH;
    for (int i = threadIdx.x; i < WW * NB; i += blockDim.x) lh[i] = 0u;
    __syncthreads();

    const int perSlice = BC / SLICES;      // 2048 (b,c) planes
    const int bc0 = slice * perSlice;
    const int total = perSlice * WW;       // 114688 elements per block
    for (int j = threadIdx.x; j < total; j += blockDim.x) {
        int bc = bc0 + j / WW;
        int w  = j % WW;
        float v = x[(size_t)bc * PLANE + h * WW + w];
        if (v >= 0.f && v <= 1.f) {        // torch.histc: out-of-range dropped
            int bin = (int)floorf(v * 256.f);
            bin = bin > 255 ? 255 : (bin < 0 ? 0 : bin);  // v==1 -> last bin
            atomicAdd(&lh[w * NB + bin], 1u);
        }
    }
    __syncthreads();
    unsigned* gh = hist + (size_t)h * (WW * NB);
    for (int i = threadIdx.x; i < WW * NB; i += blockDim.x) {
        unsigned v = lh[i];
        if (v) atomicAdd(&gh[i], v);
    }
}

// ---------------------------------------------------------------------------
// Kernels 2a/2b: in-place 2D inclusive prefix sum over (h,w) per bin.
// After both, hist[h][w][bin] = sum over rows<=h, cols<=w. Exact (u32 ints).
// Thread = bin -> fully coalesced 1KB accesses.
// ---------------------------------------------------------------------------
__global__ void cumw_kernel(unsigned* __restrict__ hist) {
    const int h = blockIdx.x, b = threadIdx.x;
    unsigned cum = 0;
    for (int w = 0; w < WW; w++) {
        unsigned* p = &hist[((size_t)(h * WW + w)) * NB + b];
        cum += *p; *p = cum;
    }
}

__global__ void cumh_kernel(unsigned* __restrict__ hist) {
    const int w = blockIdx.x, b = threadIdx.x;
    unsigned cum = 0;
    for (int h = 0; h < HH; h++) {
        unsigned* p = &hist[((size_t)(h * WW + w)) * NB + b];
        cum += *p; *p = cum;
    }
}

// ---------------------------------------------------------------------------
// Kernel 3: EKLM decisions. Single wave (64 lanes x 4 bins each).
// All reductions are shuffle butterflies -> every lane holds the full sum,
// so control flow stays wave-uniform.
// ---------------------------------------------------------------------------
__device__ __forceinline__ float wave_sum(float v) {
#pragma unroll
    for (int off = 32; off > 0; off >>= 1) v += __shfl_xor(v, off);
    return v;
}

// Integral-hist lookup in exclusive coords: I(a,b,bin) = count of rows<a, cols<b.
__device__ __forceinline__ float ilook(const unsigned* __restrict__ integ,
                                       int a, int b, int bin) {
    return (a == 0 || b == 0) ? 0.f
                              : (float)integ[((size_t)((a - 1) * WW + (b - 1))) * NB + bin];
}

// Entropy of region rows [0,xd), cols [ys,yd)  (xs fixed to 0 as in source).
__device__ float region_ent(const unsigned* __restrict__ integ, int lane,
                            int xd, int ys, int yd) {
    float hb[4];
    float hs = 0.f;
#pragma unroll
    for (int k = 0; k < 4; k++) {
        int bin = lane + 64 * k;
        float hv = ilook(integ, xd, yd, bin) - ilook(integ, xd, ys, bin);
        hb[k] = hv;
        hs += hv;
    }
    hs = wave_sum(hs);
    float e = 0.f;
#pragma unroll
    for (int k = 0; k < 4; k++) {
        float p = hb[k] / hs;
        e += p * log2f(p + 1e-9f);   // matches -sum(p*log2(p+1e-9))
    }
    return -wave_sum(e);
}

__global__ void decide_kernel(const unsigned* __restrict__ integ,
                              int* __restrict__ region) {
    const int lane = threadIdx.x;

    // ---- ent of each row-0 column cell; argmax = first occurrence ----
    float best = -3.0e38f;
    int bestw = 0;
    for (int w = 0; w < WW; w++) {
        float hb[4];
        float hs = 0.f;
#pragma unroll
        for (int k = 0; k < 4; k++) {
            int bin = lane + 64 * k;
            float hv = (float)integ[(size_t)w * NB + bin]
                     - (w > 0 ? (float)integ[(size_t)(w - 1) * NB + bin] : 0.f);
            hb[k] = hv;
            hs += hv;
        }
        hs = wave_sum(hs);
        float e = 0.f;
#pragma unroll
        for (int k = 0; k < 4; k++) {
            float p = hb[k] / hs;
            e += p * log2f(p + 1e-9f);
        }
        e = -wave_sum(e);
        if (e > best) { best = e; bestw = w; }  // strict > keeps FIRST max
    }

    const float total_ent = region_ent(integ, lane, HH, 0, WW);

    // ---- greedy grow loop (identical priority order to reference) ----
    int xd = 1, ys = bestw, yd = bestw + 1;
    float Ts = region_ent(integ, lane, xd, ys, yd) / total_ent;
    bool done = false;
    int iter = 0;
    while (Ts < 0.9f && !done && iter < 1000) {
        iter++;
        float e_cur = region_ent(integ, lane, xd, ys, yd);
        int ysm = (ys - 1 < 0) ? 0 : ys - 1;
        int ydp = (yd + 1 > WW) ? WW : yd + 1;
        bool c1 = (xd + 1 < HH) && (region_ent(integ, lane, xd + 1, ys, yd) > e_cur);
        bool c2 = !c1 && (ys - 1 >= 0) && (region_ent(integ, lane, xd, ysm, yd) > e_cur);
        bool c3 = !c1 && !c2 && (yd + 1 < WW) && (region_ent(integ, lane, xd, ys, ydp) > e_cur);
        if (c1) xd = xd + 1;
        else if (c2) ys = ys - 1;
        else if (c3) yd = yd + 1;
        done = !(c1 || c2 || c3);
        Ts = region_ent(integ, lane, xd, ys, yd) / total_ent;
    }

    if (lane == 0) {
        region[0] = xd;
        region[1] = ys;
        region[2] = yd;
    }
}

// ---------------------------------------------------------------------------
// Kernel 4: masked mean-pool. One wave per (b,c) plane; reads ONLY the
// region's elements (for the expected 1-cell region this is 8192 loads total).
// ---------------------------------------------------------------------------
__global__ void pool_kernel(const float* __restrict__ x,
                            const int* __restrict__ region,
                            float* __restrict__ pooled) {
    const int bc = blockIdx.x;
    const int xd = region[0], ys = region[1], yd = region[2];
    const int Wd = yd - ys;
    const int n = xd * Wd;
    const float area = fmaxf((float)n, 1.f);
    const float* plane = x + (size_t)bc * PLANE;
    float s = 0.f;
    for (int j = threadIdx.x; j < n; j += 64) {
        int r = j / Wd;
        int cc = ys + (j - r * Wd);
        s += plane[r * WW + cc];
    }
#pragma unroll
    for (int off = 32; off > 0; off >>= 1) s += __shfl_xor(s, off);
    if (threadIdx.x == 0) pooled[bc] = s / area;
}

// ---------------------------------------------------------------------------
// Kernel 5: tiny FC  out[b][n] = sum_c pooled[b][c] * w_fc[c][n]
// ---------------------------------------------------------------------------
__global__ void fc_kernel(const float* __restrict__ pooled,
                          const float* __restrict__ wfc,
                          float* __restrict__ out) {
    const int t = threadIdx.x;
    if (t >= BB * NCLS) return;
    const int b = t / NCLS, n = t - b * NCLS;
    const float* pv = pooled + b * CC;
    float a0 = 0.f, a1 = 0.f, a2 = 0.f, a3 = 0.f;
    for (int c = 0; c < CC; c += 4) {
        a0 += pv[c + 0] * wfc[(c + 0) * NCLS + n];
        a1 += pv[c + 1] * wfc[(c + 1) * NCLS + n];
        a2 += pv[c + 2] * wfc[(c + 2) * NCLS + n];
        a3 += pv[c + 3] * wfc[(c + 3) * NCLS + n];
    }
    out[t] = (a0 + a1) + (a2 + a3);
}

// ---------------------------------------------------------------------------
extern "C" void kernel_launch(void* const* d_in, const int* in_sizes, int n_in,
                              void* d_out, int out_size, void* d_ws, size_t ws_size,
                              hipStream_t stream) {
    const float* x   = (const float*)d_in[0];   // [8,1024,56,56]
    const float* wfc = (const float*)d_in[1];   // [1024,30]
    float* out = (float*)d_out;                 // [8,30]

    unsigned char* ws = (unsigned char*)d_ws;
    unsigned* hist  = (unsigned*)ws;                               // 3,211,264 B
    int*      region = (int*)(ws + (size_t)HISTN * 4);             // 16 B
    float*    pooled = (float*)(ws + (size_t)HISTN * 4 + 1024);    // 32,768 B

    // ws is poisoned to 0xAA before every timed launch -> must zero the hist.
    hipMemsetAsync(hist, 0, (size_t)HISTN * 4, stream);

    hist_kernel<<<HH * SLICES, 512, 0, stream>>>(x, hist);
    cumw_kernel<<<HH, NB, 0, stream>>>(hist);
    cumh_kernel<<<WW, NB, 0, stream>>>(hist);
    decide_kernel<<<1, 64, 0, stream>>>(hist, region);
    pool_kernel<<<BC, 64, 0, stream>>>(x, region, pooled);
    fc_kernel<<<1, 256, 0, stream>>>(pooled, wfc, out);
}

// Round 2
// 188.818 us; speedup vs baseline: 1.8570x; 1.8570x over previous
//
#include <hip/hip_runtime.h>
#include <math.h>

#define BB 8
#define CC 1024
#define HH 56
#define WW 56
#define NB 256
#define NCLS 30
#define BC (BB * CC)             // 8192 planes
#define PLANE (HH * WW)          // 3136
#define NWORD (NB / 2)           // 128 packed u16-pairs per cell
#define CELLW (HH * WW * NWORD)  // 401408 packed words for the whole image
#define SLICES 16
#define WSPLIT 2
#define WHALF (WW / WSPLIT)      // 28 columns per block
#define PL_PER_SLICE (BC / SLICES)              // 512 planes
#define HTHREADS 256
#define VEC4_PER_BLOCK (PL_PER_SLICE * WHALF / 4)  // 3584 float4 loads/block
#define LH_WORDS (WHALF * NWORD)                   // 3584 u32 (14 KB LDS)

// ---------------------------------------------------------------------------
// Kernel 1: per-(h,w)-cell histograms, u16-packed in u32 words.
// Block = (whalf, h, slice). LDS hist [28][128] u32 = 14 KB -> ~7 blocks/CU.
// Packing safety: per (cell,bin) count <= 512 per slice (and <= 8192 total),
// so the low u16 never carries into the high u16 under +1 / +65536 adds.
// Flush: ATOMIC_FLUSH=false -> plain stores to a per-slice buffer (no atomics);
//        ATOMIC_FLUSH=true  -> packed atomicAdd into one global packed hist.
// ---------------------------------------------------------------------------
template <bool ATOMIC_FLUSH>
__global__ __launch_bounds__(HTHREADS) void hist_kernel(const float* __restrict__ x,
                                                        unsigned* __restrict__ dst) {
    __shared__ unsigned lh[LH_WORDS];
    const int tid = threadIdx.x;
    const int bid = blockIdx.x;
    const int whalf = bid & (WSPLIT - 1);
    const int hs = bid / WSPLIT;     // slice*HH + h
    const int h = hs % HH;
    const int slice = hs / HH;

    for (int i = tid; i < LH_WORDS; i += HTHREADS) lh[i] = 0u;
    __syncthreads();

    const float* __restrict__ xb =
        x + (size_t)(slice * PL_PER_SLICE) * PLANE + h * WW + whalf * WHALF;

#pragma unroll
    for (int it = 0; it < VEC4_PER_BLOCK / HTHREADS; ++it) {   // 14 iters
        const int j = it * HTHREADS + tid;                     // [0, 3584)
        const int bcl = j / 7;                                 // plane in slice
        const int wq = j - bcl * 7;                            // float4 idx in row-half
        const float4 v = *(const float4*)(xb + (size_t)bcl * PLANE + wq * 4);
        const float vv[4] = {v.x, v.y, v.z, v.w};
#pragma unroll
        for (int e = 0; e < 4; ++e) {
            const float f = vv[e];
            if (f >= 0.f && f <= 1.f) {                        // histc: OOR dropped
                int bin = (int)(f * 256.f);                    // floor (f>=0)
                if (bin > 255) bin = 255;                      // v==1 -> last bin
                const int wl = wq * 4 + e;
                atomicAdd(&lh[wl * NWORD + (bin >> 1)], 1u << ((bin & 1) << 4));
            }
        }
    }
    __syncthreads();

    if (ATOMIC_FLUSH) {
        unsigned* g = dst + ((size_t)h * WW + whalf * WHALF) * NWORD;
        for (int i = tid; i < LH_WORDS; i += HTHREADS) {
            const unsigned v = lh[i];
            if (v) atomicAdd(&g[i], v);
        }
    } else {
        unsigned* g = dst + ((size_t)hs * WW + whalf * WHALF) * NWORD;
        for (int i = tid; i < LH_WORDS; i += HTHREADS) g[i] = lh[i];
    }
}

// ---------------------------------------------------------------------------
// Kernel 2: sum the per-slice packed hists and unpack to u32 [h][w][256].
// hist[2*idx] / hist[2*idx+1] are exactly the low/high u16 bins of word idx.
// ---------------------------------------------------------------------------
__global__ void reduce_kernel(const unsigned* __restrict__ ps,
                              unsigned* __restrict__ hist) {
    const int idx = blockIdx.x * 256 + threadIdx.x;  // < CELLW (exact grid)
    unsigned s = 0;
#pragma unroll
    for (int sl = 0; sl < SLICES; ++sl) s += ps[(size_t)sl * CELLW + idx];
    ((uint2*)hist)[idx] = make_uint2(s & 0xffffu, s >> 16);
}

__global__ void unpack_kernel(const unsigned* __restrict__ hp,
                              unsigned* __restrict__ hist) {
    const int idx = blockIdx.x * 256 + threadIdx.x;
    const unsigned s = hp[idx];
    ((uint2*)hist)[idx] = make_uint2(s & 0xffffu, s >> 16);
}

// ---------------------------------------------------------------------------
// Kernels 3a/3b: in-place 2D inclusive prefix sum. Register-staged: all 56
// loads issued independently (no dependent-load chain), then cum + store.
// ---------------------------------------------------------------------------
__global__ void cumw_kernel(unsigned* __restrict__ hist) {
    const int h = blockIdx.x, b = threadIdx.x;
    unsigned* base = hist + (size_t)h * WW * NB + b;
    unsigned v[WW];
#pragma unroll
    for (int w = 0; w < WW; ++w) v[w] = base[(size_t)w * NB];
    unsigned c = 0;
#pragma unroll
    for (int w = 0; w < WW; ++w) { c += v[w]; base[(size_t)w * NB] = c; }
}

__global__ void cumh_kernel(unsigned* __restrict__ hist) {
    const int w = blockIdx.x, b = threadIdx.x;
    unsigned* base = hist + (size_t)w * NB + b;
    unsigned v[HH];
#pragma unroll
    for (int h = 0; h < HH; ++h) v[h] = base[(size_t)h * WW * NB];
    unsigned c = 0;
#pragma unroll
    for (int h = 0; h < HH; ++h) { c += v[h]; base[(size_t)h * WW * NB] = c; }
}

// ---------------------------------------------------------------------------
// Kernel 4: EKLM decisions. 16 waves compute the 56 column entropies in
// parallel; wave 0 then does the argmax + greedy loop (wave-uniform).
// ---------------------------------------------------------------------------
__device__ __forceinline__ float wave_sum(float v) {
#pragma unroll
    for (int off = 32; off > 0; off >>= 1) v += __shfl_xor(v, off);
    return v;
}

__device__ __forceinline__ float ilook(const unsigned* __restrict__ integ,
                                       int a, int b, int bin) {
    return (a == 0 || b == 0)
               ? 0.f
               : (float)integ[((size_t)((a - 1) * WW + (b - 1))) * NB + bin];
}

__device__ float region_ent(const unsigned* __restrict__ integ, int lane,
                            int xd, int ys, int yd) {
    float hb[4];
    float hs = 0.f;
#pragma unroll
    for (int k = 0; k < 4; k++) {
        const int bin = lane + 64 * k;
        const float hv = ilook(integ, xd, yd, bin) - ilook(integ, xd, ys, bin);
        hb[k] = hv;
        hs += hv;
    }
    hs = wave_sum(hs);
    float e = 0.f;
#pragma unroll
    for (int k = 0; k < 4; k++) {
        const float p = hb[k] / hs;
        e += p * log2f(p + 1e-9f);
    }
    return -wave_sum(e);
}

__global__ __launch_bounds__(1024) void decide_kernel(const unsigned* __restrict__ integ,
                                                      int* __restrict__ region) {
    __shared__ float ent_s[WW];
    const int tid = threadIdx.x;
    const int lane = tid & 63;
    const int wv = tid >> 6;

    for (int w = wv; w < WW; w += 16) {
        float hb[4], hs = 0.f;
#pragma unroll
        for (int k = 0; k < 4; k++) {
            const int bin = lane + 64 * k;
            const float a = (float)integ[(size_t)w * NB + bin];
            const float b = w ? (float)integ[(size_t)(w - 1) * NB + bin] : 0.f;
            hb[k] = a - b;
            hs += hb[k];
        }
        hs = wave_sum(hs);
        float e = 0.f;
#pragma unroll
        for (int k = 0; k < 4; k++) {
            const float p = hb[k] / hs;
            e += p * log2f(p + 1e-9f);
        }
        e = -wave_sum(e);
        if (lane == 0) ent_s[w] = e;
    }
    __syncthreads();
    if (wv != 0) return;

    float best = -3.0e38f;
    int bestw = 0;
    for (int w = 0; w < WW; ++w) {
        const float e = ent_s[w];
        if (e > best) { best = e; bestw = w; }  // strict > keeps FIRST max
    }

    const float total_ent = region_ent(integ, lane, HH, 0, WW);

    int xd = 1, ys = bestw, yd = bestw + 1;
    float Ts = region_ent(integ, lane, xd, ys, yd) / total_ent;
    bool done = false;
    int iter = 0;
    while (Ts < 0.9f && !done && iter < 1000) {
        iter++;
        const float e_cur = region_ent(integ, lane, xd, ys, yd);
        const int ysm = (ys - 1 < 0) ? 0 : ys - 1;
        const int ydp = (yd + 1 > WW) ? WW : yd + 1;
        const bool c1 = (xd + 1 < HH) && (region_ent(integ, lane, xd + 1, ys, yd) > e_cur);
        const bool c2 = !c1 && (ys - 1 >= 0) && (region_ent(integ, lane, xd, ysm, yd) > e_cur);
        const bool c3 = !c1 && !c2 && (yd + 1 < WW) && (region_ent(integ, lane, xd, ys, ydp) > e_cur);
        if (c1) xd = xd + 1;
        else if (c2) ys = ys - 1;
        else if (c3) yd = yd + 1;
        done = !(c1 || c2 || c3);
        Ts = region_ent(integ, lane, xd, ys, yd) / total_ent;
    }

    if (lane == 0) {
        region[0] = xd;
        region[1] = ys;
        region[2] = yd;
    }
}

// ---------------------------------------------------------------------------
// Kernel 5: masked mean-pool — one wave per (b,c) plane, reads only region.
// ---------------------------------------------------------------------------
__global__ void pool_kernel(const float* __restrict__ x,
                            const int* __restrict__ region,
                            float* __restrict__ pooled) {
    const int bc = blockIdx.x;
    const int xd = region[0], ys = region[1], yd = region[2];
    const int Wd = yd - ys;
    const int n = xd * Wd;
    const float area = fmaxf((float)n, 1.f);
    const float* plane = x + (size_t)bc * PLANE;
    float s = 0.f;
    for (int j = threadIdx.x; j < n; j += 64) {
        const int r = j / Wd;
        const int cc = ys + (j - r * Wd);
        s += plane[r * WW + cc];
    }
#pragma unroll
    for (int off = 32; off > 0; off >>= 1) s += __shfl_xor(s, off);
    if (threadIdx.x == 0) pooled[bc] = s / area;
}

// ---------------------------------------------------------------------------
// Kernel 6: FC. Block = batch b; 8 c-chunks x 30 classes; LDS reduce.
// ---------------------------------------------------------------------------
__global__ __launch_bounds__(256) void fc_kernel(const float* __restrict__ pooled,
                                                 const float* __restrict__ wfc,
                                                 float* __restrict__ out) {
    __shared__ float red[240];
    const int b = blockIdx.x;
    const int t = threadIdx.x;
    if (t < 240) {
        const int chunk = t / NCLS;       // 0..7 -> c range [chunk*128, +128)
        const int n = t - chunk * NCLS;
        const float* pv = pooled + b * CC + chunk * 128;
        const float* wv = wfc + (size_t)(chunk * 128) * NCLS + n;
        float a0 = 0.f, a1 = 0.f, a2 = 0.f, a3 = 0.f;
        for (int c = 0; c < 128; c += 4) {
            a0 += pv[c + 0] * wv[(c + 0) * NCLS];
            a1 += pv[c + 1] * wv[(c + 1) * NCLS];
            a2 += pv[c + 2] * wv[(c + 2) * NCLS];
            a3 += pv[c + 3] * wv[(c + 3) * NCLS];
        }
        red[t] = (a0 + a1) + (a2 + a3);
    }
    __syncthreads();
    if (t < NCLS) {
        float s = 0.f;
#pragma unroll
        for (int ch = 0; ch < 8; ++ch) s += red[ch * NCLS + t];
        out[b * NCLS + t] = s;
    }
}

// ---------------------------------------------------------------------------
extern "C" void kernel_launch(void* const* d_in, const int* in_sizes, int n_in,
                              void* d_out, int out_size, void* d_ws, size_t ws_size,
                              hipStream_t stream) {
    const float* x = (const float*)d_in[0];    // [8,1024,56,56]
    const float* wfc = (const float*)d_in[1];  // [1024,30]
    float* out = (float*)d_out;                // [8,30]

    unsigned char* ws = (unsigned char*)d_ws;
    const size_t ps_bytes = (size_t)SLICES * CELLW * 4;  // 25.7 MB
    const size_t hist_bytes = (size_t)CELLW * 8;         // 3.2 MB (u32 x 802816)
    const size_t needA = ps_bytes + hist_bytes + 4096 + (size_t)BC * 4;

    if (ws_size >= needA) {
        // Variant A: per-slice non-atomic flush + reduce (no atomics, no memset)
        unsigned* ps = (unsigned*)ws;
        unsigned* hist = (unsigned*)(ws + ps_bytes);
        int* region = (int*)(ws + ps_bytes + hist_bytes);
        float* pooled = (float*)(ws + ps_bytes + hist_bytes + 4096);

        hist_kernel<false><<<HH * WSPLIT * SLICES, HTHREADS, 0, stream>>>(x, ps);
        reduce_kernel<<<CELLW / 256, 256, 0, stream>>>(ps, hist);
        cumw_kernel<<<HH, NB, 0, stream>>>(hist);
        cumh_kernel<<<WW, NB, 0, stream>>>(hist);
        decide_kernel<<<1, 1024, 0, stream>>>(hist, region);
        pool_kernel<<<BC, 64, 0, stream>>>(x, region, pooled);
        fc_kernel<<<BB, 256, 0, stream>>>(pooled, wfc, out);
    } else {
        // Variant B (small ws fallback): packed atomic flush into one hist
        unsigned* hp = (unsigned*)ws;                        // 1.6 MB packed
        unsigned* hist = (unsigned*)(ws + (size_t)CELLW * 4);
        int* region = (int*)(ws + (size_t)CELLW * 4 + hist_bytes);
        float* pooled = (float*)(ws + (size_t)CELLW * 4 + hist_bytes + 4096);

        hipMemsetAsync(hp, 0, (size_t)CELLW * 4, stream);
        hist_kernel<true><<<HH * WSPLIT * SLICES, HTHREADS, 0, stream>>>(x, hp);
        unpack_kernel<<<CELLW / 256, 256, 0, stream>>>(hp, hist);
        cumw_kernel<<<HH, NB, 0, stream>>>(hist);
        cumh_kernel<<<WW, NB, 0, stream>>>(hist);
        decide_kernel<<<1, 1024, 0, stream>>>(hist, region);
        pool_kernel<<<BC, 64, 0, stream>>>(x, region, pooled);
        fc_kernel<<<BB, 256, 0, stream>>>(pooled, wfc, out);
    }
}